// Round 8
// baseline (129.930 us; speedup 1.0000x reference)
//
#include <hip/hip_runtime.h>
#include <float.h>

#define Bb 2
#define Ll 256
#define Ss 384
#define Hh 768
#define Tc 16
#define Dc 50
#define WD 100
#define CV 128
#define NG 200     // 4*Dc gates
#define OUTC 968   // H + WD + 2*Dc

// ws layout (floats):
//   [0, 128)      minv partials
//   [128, ...)    xproj table [2][128][200], bias folded in

__device__ inline float tanh_fast(float x) {
    float e = __expf(2.f * x);
    return 1.f - 2.f / (e + 1.f);
}
__device__ inline float sigmoid_fast(float x) {
    return 1.f / (1.f + __expf(-x));
}

// ================= kernel 1: min partials | xproj =================
// grid 144: [0,128) min, [128,144) xproj

__global__ __launch_bounds__(256) void kernel1(
        const float* __restrict__ bert, const float* __restrict__ char_table,
        const float* __restrict__ Wih_f, const float* __restrict__ bih_f, const float* __restrict__ bhh_f,
        const float* __restrict__ Wih_b, const float* __restrict__ bih_b, const float* __restrict__ bhh_b,
        float* __restrict__ minp, float* __restrict__ xpt) {
    int blk = blockIdx.x, tid = threadIdx.x;
    if (blk < 128) {
        const int n4 = (Bb * Ss * Hh) / 4;       // 147456 float4
        const float4* b4 = (const float4*)bert;
        float m = FLT_MAX;
        for (int i = blk * 256 + tid; i < n4; i += 128 * 256) {
            float4 v = b4[i];
            m = fminf(m, fminf(fminf(v.x, v.y), fminf(v.z, v.w)));
        }
        #pragma unroll
        for (int off = 32; off; off >>= 1) m = fminf(m, __shfl_down(m, off, 64));
        __shared__ float red[4];
        if ((tid & 63) == 0) red[tid >> 6] = m;
        __syncthreads();
        if (tid == 0) minp[blk] = fminf(fminf(red[0], red[1]), fminf(red[2], red[3]));
    } else {
        int idx = blk - 128;            // dir*8 + cid-chunk
        int dir = idx >> 3, c0 = (idx & 7) * 16;
        const float* Wih = dir ? Wih_b : Wih_f;
        const float* bih = dir ? bih_b : bih_f;
        const float* bhh = dir ? bhh_b : bhh_f;
        __shared__ float ct[16][Dc];
        for (int e = tid; e < 16 * Dc; e += 256)
            ((float*)ct)[e] = char_table[c0 * Dc + e];
        __syncthreads();
        if (tid < NG) {
            float w[Dc];
            #pragma unroll
            for (int j = 0; j < Dc; j++) w[j] = Wih[tid * Dc + j];
            float bias = bih[tid] + bhh[tid];
            for (int cid = 0; cid < 16; cid++) {
                float a = bias;
                #pragma unroll
                for (int j = 0; j < Dc; j++) a += w[j] * ct[cid][j];
                xpt[(dir * CV + c0 + cid) * NG + tid] = a;
            }
        }
    }
}

// ================= kernel_lstm: char bi-LSTM =================
// grid 1024: n = blk>>1, dir = blk&1.
// h-broadcast via v_readlane (compile-time lane index), NOT ds_read_b128:
// the old 13-b128 broadcast per wave per step was LDS-return-path bound
// (~208 LDS instrs/CU/step = ~2500 cyc/step = 17+ us wall). readlane moves
// the broadcast to the 4 parallel VALU pipes. State update is redundant
// per-wave (h lane-resident), so hs never crosses waves -> ONE barrier/step
// with double-buffered gs. xproj stays in LDS (runtime t index); w[50] is
// constant-indexed in a fully unrolled loop (register-resident).

__global__ __launch_bounds__(256, 4) void kernel_lstm(
        const int* __restrict__ char_ids, const int* __restrict__ char_count,
        const float* __restrict__ Whh_f, const float* __restrict__ Whh_b,
        const float* __restrict__ xpt, float* __restrict__ out) {
    __shared__ __align__(16) float xg[Tc][NG];     // 12800 B
    __shared__ __align__(16) float gsb[2][NG];     // 1600 B
    __shared__ int scid[Tc];

    int blk = blockIdx.x, tid = threadIdx.x;
    int n = blk >> 1, dir = blk & 1;
    const float* Whh = dir ? Whh_b : Whh_f;
    int lane = tid & 63;

    int len = char_count[n];
    if (len < 1) len = 1;
    if (tid < Tc) {
        int st = dir ? (tid < len ? len - 1 - tid : tid) : tid;   // bwd: reverse valid prefix
        scid[tid] = char_ids[n * Tc + st];
    }
    __syncthreads();

    // stage xproj rows as float4 (row stride 200 floats = 800B, 16B aligned)
    for (int e = tid; e < Tc * (NG / 4); e += 256) {
        int t = e / 50, q = e - t * 50;
        ((float4*)xg[t])[q] = ((const float4*)&xpt[(dir * CV + scid[t]) * NG])[q];
    }
    // recurrent weight row -> regs, defined for ALL lanes (clamped row),
    // constant indices only (fully unrolled) => register-resident
    int wrow = tid < NG ? tid : NG - 1;
    bool istanh = (tid >= 100 && tid < 150);          // cell-gate rows
    float w[50];
    #pragma unroll
    for (int j = 0; j < 50; j++) w[j] = Whh[wrow * 50 + j];
    __syncthreads();

    int ch = lane < 50 ? lane : 49;                   // state channel this lane tracks
    float c = 0.f, h = 0.f, maxv = -FLT_MAX;
    for (int t = 0; t < Tc; t++) {
        // ---- A: gate pre-activation, h broadcast from own wave's lanes ----
        int hb = __float_as_int(h);
        float g0 = xg[t][wrow], g1 = 0.f, g2 = 0.f, g3 = 0.f;
        #pragma unroll
        for (int j = 0; j < 48; j += 4) {
            g0 = fmaf(__int_as_float(__builtin_amdgcn_readlane(hb, j)),     w[j],     g0);
            g1 = fmaf(__int_as_float(__builtin_amdgcn_readlane(hb, j + 1)), w[j + 1], g1);
            g2 = fmaf(__int_as_float(__builtin_amdgcn_readlane(hb, j + 2)), w[j + 2], g2);
            g3 = fmaf(__int_as_float(__builtin_amdgcn_readlane(hb, j + 3)), w[j + 3], g3);
        }
        g0 = fmaf(__int_as_float(__builtin_amdgcn_readlane(hb, 48)), w[48], g0);
        g1 = fmaf(__int_as_float(__builtin_amdgcn_readlane(hb, 49)), w[49], g1);
        float g = (g0 + g1) + (g2 + g3);
        if (tid < NG)
            gsb[t & 1][tid] = istanh ? tanh_fast(g) : sigmoid_fast(g);
        __syncthreads();                               // the only barrier per step
        // ---- B: state update, redundant in every wave (h stays lane-local).
        // gs double-buffer makes this race-free: A(t+2)'s write to gsb[t&1]
        // is after barrier(t+1), which follows every wave's B(t) reads.
        float si = gsb[t & 1][ch];
        float sf = gsb[t & 1][ch + 50];
        float tg = gsb[t & 1][ch + 100];
        float so = gsb[t & 1][ch + 150];
        c = sf * c + si * tg;
        h = so * tanh_fast(c);
        if (t < len) maxv = fmaxf(maxv, h);            // ragged max
    }
    if (tid < 50)
        out[(size_t)n * OUTC + (Hh + WD) + dir * Dc + tid] = maxv;
}

// ================= kernel_word: word_reps masked max | embed =================
// grid 832: [0,768) word (4 l-rows per block), [768,832) embed.
// 4 rows/block (not 8): the 8-row variant's 448-block grid gave only
// 1.75 blocks/CU -- occupancy-starved. 768 blocks = 3 blocks/CU,
// 12 waves/CU, and the branchless accumulate (no SALU, no branches) keeps
// the inner loop pure VALU: acc = fmax(acc, v + bias), bias in {0, -FLT_MAX}.

__global__ __launch_bounds__(256) void kernel_word(
        const float* __restrict__ bert, const int* __restrict__ p2w,
        const float* __restrict__ minp,
        const int* __restrict__ word_ids, const float* __restrict__ word_table,
        float* __restrict__ out) {
    __shared__ __align__(16) float sm[Ss][4];         // mask bias [s][row], 6144 B
    __shared__ __align__(16) float sacc[4][4][128];   // 8192 B
    __shared__ float sminv;
    int blk = blockIdx.x, tid = threadIdx.x;

    if (blk < 768) {
        int hc  = blk % 6;             // h-chunk of 128
        int lt  = (blk / 6) & 63;      // l-tile of 4
        int b   = blk / 384;
        int l0  = lt * 4;

        // stage mask bias, coalesced global reads (s-fast within a row)
        const int* pm = p2w + ((size_t)(b * Ll + l0)) * Ss;
        for (int e = tid; e < 4 * Ss; e += 256) {
            int r = e / Ss, s = e - r * Ss;
            sm[s][r] = pm[r * Ss + s] ? 0.f : -FLT_MAX;
        }
        if (tid < 64) {
            float m = fminf(minp[tid], minp[tid + 64]);
            #pragma unroll
            for (int off = 32; off; off >>= 1) m = fminf(m, __shfl_down(m, off, 64));
            if (tid == 0) sminv = m;
        }
        __syncthreads();

        int w    = tid >> 6;           // wave -> s range [w*96, w*96+96)
        int lane = tid & 63;
        int s0 = w * 96;

        const float2* bb2 = (const float2*)(bert + (size_t)b * Ss * Hh) + hc * 64 + lane;
        float2 acc[4];
        #pragma unroll
        for (int r = 0; r < 4; r++) { acc[r].x = -FLT_MAX; acc[r].y = -FLT_MAX; }

        for (int jo = 0; jo < 96; jo += 8) {       // 8 loads in flight per group
            float2 v[8];
            #pragma unroll
            for (int k = 0; k < 8; k++) v[k] = bb2[(size_t)(s0 + jo + k) * 384];
            #pragma unroll
            for (int k = 0; k < 8; k++) {
                int j = s0 + jo + k;
                float4 q = *(const float4*)&sm[j][0];   // broadcast, rows 0..3
                acc[0].x = fmaxf(acc[0].x, v[k].x + q.x);
                acc[0].y = fmaxf(acc[0].y, v[k].y + q.x);
                acc[1].x = fmaxf(acc[1].x, v[k].x + q.y);
                acc[1].y = fmaxf(acc[1].y, v[k].y + q.y);
                acc[2].x = fmaxf(acc[2].x, v[k].x + q.z);
                acc[2].y = fmaxf(acc[2].y, v[k].y + q.z);
                acc[3].x = fmaxf(acc[3].x, v[k].x + q.w);
                acc[3].y = fmaxf(acc[3].y, v[k].y + q.w);
            }
        }
        #pragma unroll
        for (int r = 0; r < 4; r++)
            *(float2*)&sacc[w][r][lane * 2] = acc[r];
        __syncthreads();

        float mv = sminv;
        for (int e = tid; e < 4 * 128; e += 256) {
            int r = e >> 7, cx = e & 127;
            float m = fmaxf(fmaxf(sacc[0][r][cx], sacc[1][r][cx]),
                            fmaxf(sacc[2][r][cx], sacc[3][r][cx]));
            if (m == -FLT_MAX) m = mv;             // fully-masked row -> global min fill
            out[((size_t)(b * Ll + l0 + r)) * OUTC + hc * 128 + cx] = m;
        }
    } else {
        // ---------------- word embedding gather ----------------
        for (int i = (blk - 768) * 256 + tid; i < Bb * Ll * WD; i += 64 * 256) {
            int bl = i / WD, d = i - bl * WD;
            out[(size_t)bl * OUTC + Hh + d] = word_table[(size_t)word_ids[bl] * WD + d];
        }
    }
}

extern "C" void kernel_launch(void* const* d_in, const int* in_sizes, int n_in,
                              void* d_out, int out_size, void* d_ws, size_t ws_size,
                              hipStream_t stream) {
    const float* bert       = (const float*)d_in[0];
    const int*   p2w        = (const int*)d_in[1];
    const int*   word_ids   = (const int*)d_in[2];
    const int*   char_count = (const int*)d_in[3];
    const int*   char_ids   = (const int*)d_in[4];
    // d_in[5] token_masks_char: consistent with char_count, unused
    const float* word_table = (const float*)d_in[6];
    const float* char_table = (const float*)d_in[7];
    const float* Wih_f = (const float*)d_in[8];
    const float* Whh_f = (const float*)d_in[9];
    const float* bih_f = (const float*)d_in[10];
    const float* bhh_f = (const float*)d_in[11];
    const float* Wih_b = (const float*)d_in[12];
    const float* Whh_b = (const float*)d_in[13];
    const float* bih_b = (const float*)d_in[14];
    const float* bhh_b = (const float*)d_in[15];
    float* out = (float*)d_out;

    float* minp = (float*)d_ws;          // 128 floats
    float* xpt  = minp + 128;            // 2*128*200 floats

    kernel1<<<144, 256, 0, stream>>>(
        bert, char_table, Wih_f, bih_f, bhh_f, Wih_b, bih_b, bhh_b,
        minp, xpt);
    kernel_lstm<<<1024, 256, 0, stream>>>(
        char_ids, char_count, Whh_f, Whh_b, xpt, out);
    kernel_word<<<832, 256, 0, stream>>>(
        bert, p2w, minp, word_ids, word_table, out);
}

// Round 9
// 123.463 us; speedup vs baseline: 1.0524x; 1.0524x over previous
//
#include <hip/hip_runtime.h>
#include <float.h>

#define Bb 2
#define Ll 256
#define Ss 384
#define Hh 768
#define Tc 16
#define Dc 50
#define WD 100
#define CV 128
#define NG 200     // 4*Dc gates
#define OUTC 968   // H + WD + 2*Dc

// ws layout (floats):
//   [0, 128)      minv partials
//   [128, ...)    xproj table [2][128][200], bias folded in

__device__ inline float tanh_fast(float x) {
    float e = __expf(2.f * x);
    return 1.f - 2.f / (e + 1.f);
}
__device__ inline float sigmoid_fast(float x) {
    return 1.f / (1.f + __expf(-x));
}

// ================= kernel 1: min partials | xproj =================
// grid 144: [0,128) min, [128,144) xproj

__global__ __launch_bounds__(256) void kernel1(
        const float* __restrict__ bert, const float* __restrict__ char_table,
        const float* __restrict__ Wih_f, const float* __restrict__ bih_f, const float* __restrict__ bhh_f,
        const float* __restrict__ Wih_b, const float* __restrict__ bih_b, const float* __restrict__ bhh_b,
        float* __restrict__ minp, float* __restrict__ xpt) {
    int blk = blockIdx.x, tid = threadIdx.x;
    if (blk < 128) {
        const int n4 = (Bb * Ss * Hh) / 4;       // 147456 float4
        const float4* b4 = (const float4*)bert;
        float m = FLT_MAX;
        for (int i = blk * 256 + tid; i < n4; i += 128 * 256) {
            float4 v = b4[i];
            m = fminf(m, fminf(fminf(v.x, v.y), fminf(v.z, v.w)));
        }
        #pragma unroll
        for (int off = 32; off; off >>= 1) m = fminf(m, __shfl_down(m, off, 64));
        __shared__ float red[4];
        if ((tid & 63) == 0) red[tid >> 6] = m;
        __syncthreads();
        if (tid == 0) minp[blk] = fminf(fminf(red[0], red[1]), fminf(red[2], red[3]));
    } else {
        int idx = blk - 128;            // dir*8 + cid-chunk
        int dir = idx >> 3, c0 = (idx & 7) * 16;
        const float* Wih = dir ? Wih_b : Wih_f;
        const float* bih = dir ? bih_b : bih_f;
        const float* bhh = dir ? bhh_b : bhh_f;
        __shared__ float ct[16][Dc];
        for (int e = tid; e < 16 * Dc; e += 256)
            ((float*)ct)[e] = char_table[c0 * Dc + e];
        __syncthreads();
        if (tid < NG) {
            float w[Dc];
            #pragma unroll
            for (int j = 0; j < Dc; j++) w[j] = Wih[tid * Dc + j];
            float bias = bih[tid] + bhh[tid];
            for (int cid = 0; cid < 16; cid++) {
                float a = bias;
                #pragma unroll
                for (int j = 0; j < Dc; j++) a += w[j] * ct[cid][j];
                xpt[(dir * CV + c0 + cid) * NG + tid] = a;
            }
        }
    }
}

// ================= kernel2: fused lstm | word | embed =================
// grid 1856, roles INTERLEAVED so latency-bound lstm blocks co-reside with
// throughput-bound word blocks on every CU (R5 evidence: fused = 66 us when
// the serial parts summed to 76):
//   blk < 1536 : even -> word id blk/2 (0..767), odd -> lstm id blk/2 (0..767)
//   blk < 1792 : lstm id 768 + (blk-1536)
//   else       : embed id blk-1792
// lstm: R5/R6-proven LDS-float4 form (2 barriers/step, w[52] pinned per step).
// word: R7-proven branchless form, 4 rows/block (pure VALU inner loop).
// launch_bounds(256,4): 4 blocks/CU, VGPR cap 128, LDS 4 x 14.3KB < 160KB.

__global__ __launch_bounds__(256, 4) void kernel2(
        const int* __restrict__ char_ids, const int* __restrict__ char_count,
        const float* __restrict__ Whh_f, const float* __restrict__ Whh_b,
        const float* __restrict__ xpt,
        const float* __restrict__ bert, const int* __restrict__ p2w,
        const float* __restrict__ minp,
        const int* __restrict__ word_ids, const float* __restrict__ word_table,
        float* __restrict__ out) {
    __shared__ __align__(16) char smem[14592];
    int blk = blockIdx.x, tid = threadIdx.x;

    int role, id;
    if (blk < 1536) { role = blk & 1; id = blk >> 1; }          // 0=word, 1=lstm
    else if (blk < 1792) { role = 1; id = 768 + (blk - 1536); }
    else { role = 2; id = blk - 1792; }

    if (role == 1) {
        // ---------------- char bi-LSTM ----------------
        float (*xg)[NG] = (float (*)[NG])smem;            // 12800
        float* gs  = (float*)(smem + 12800);              // 800
        float* hs  = (float*)(smem + 13600);              // 208 (52 floats)
        int*   scid = (int*)(smem + 13808);               // 64

        int n = id >> 1, dir = id & 1;
        const float* Whh = dir ? Whh_b : Whh_f;

        int len = char_count[n];
        if (len < 1) len = 1;
        if (tid < Tc) {
            int st = dir ? (tid < len ? len - 1 - tid : tid) : tid;  // bwd: reverse valid prefix
            scid[tid] = char_ids[n * Tc + st];
        }
        if (tid < 52) hs[tid] = 0.f;
        __syncthreads();

        // stage xproj rows as float4 (row stride 200 floats = 800B, 16B aligned)
        for (int e = tid; e < Tc * (NG / 4); e += 256) {
            int t = e / 50, q = e - t * 50;
            ((float4*)xg[t])[q] = ((const float4*)&xpt[(dir * CV + scid[t]) * NG])[q];
        }
        // recurrent weight row -> regs, defined for ALL lanes (clamped row)
        int wrow = tid < NG ? tid : NG - 1;
        bool istanh = (tid >= 100 && tid < 150);          // cell-gate rows
        float w[52];
        #pragma unroll
        for (int j = 0; j < Dc; j++) w[j] = Whh[wrow * Dc + j];
        w[50] = 0.f; w[51] = 0.f;
        __syncthreads();

        float c = 0.f, maxv = -FLT_MAX;
        for (int t = 0; t < Tc; t++) {
            #pragma unroll
            for (int j = 0; j < 52; j++) asm volatile("" : "+v"(w[j]));
            if (tid < NG) {
                float g = xg[t][tid];
                #pragma unroll
                for (int j = 0; j < 52; j += 4) {
                    float4 hv = *(const float4*)&hs[j];   // broadcast reads
                    g += hv.x * w[j] + hv.y * w[j+1] + hv.z * w[j+2] + hv.w * w[j+3];
                }
                gs[tid] = istanh ? tanh_fast(g) : sigmoid_fast(g);
            }
            __syncthreads();
            if (tid < Dc) {
                float si = gs[tid];
                float sf = gs[tid + 50];
                float tg = gs[tid + 100];
                float so = gs[tid + 150];
                c = sf * c + si * tg;
                float h = so * tanh_fast(c);
                hs[tid] = h;
                if (t < len) maxv = fmaxf(maxv, h);       // ragged max
            }
            __syncthreads();
        }
        if (tid < Dc)
            out[(size_t)n * OUTC + (Hh + WD) + dir * Dc + tid] = maxv;
    } else if (role == 0) {
        // ---------------- word_reps masked max, branchless, 4 rows ----------------
        float (*sm)[4] = (float (*)[4])smem;              // [384][4] = 6144
        float (*sacc)[4][128] = (float (*)[4][128])(smem + 6144);  // 8192
        float* sminv = (float*)(smem + 14336);

        int hc  = id % 6;              // h-chunk of 128
        int lt  = (id / 6) & 63;       // l-tile of 4
        int b   = id / 384;
        int l0  = lt * 4;

        // stage mask bias, coalesced global reads (s-fast within a row)
        const int* pm = p2w + ((size_t)(b * Ll + l0)) * Ss;
        for (int e = tid; e < 4 * Ss; e += 256) {
            int r = e / Ss, s = e - r * Ss;
            sm[s][r] = pm[r * Ss + s] ? 0.f : -FLT_MAX;
        }
        if (tid < 64) {
            float m = fminf(minp[tid], minp[tid + 64]);
            #pragma unroll
            for (int off = 32; off; off >>= 1) m = fminf(m, __shfl_down(m, off, 64));
            if (tid == 0) *sminv = m;
        }
        __syncthreads();

        int w    = tid >> 6;           // wave -> s range [w*96, w*96+96)
        int lane = tid & 63;
        int s0 = w * 96;

        const float2* bb2 = (const float2*)(bert + (size_t)b * Ss * Hh) + hc * 64 + lane;
        float2 acc[4];
        #pragma unroll
        for (int r = 0; r < 4; r++) { acc[r].x = -FLT_MAX; acc[r].y = -FLT_MAX; }

        for (int jo = 0; jo < 96; jo += 8) {       // 8 loads in flight per group
            float2 v[8];
            #pragma unroll
            for (int k = 0; k < 8; k++) v[k] = bb2[(size_t)(s0 + jo + k) * 384];
            #pragma unroll
            for (int k = 0; k < 8; k++) {
                int j = s0 + jo + k;
                float4 q = *(const float4*)&sm[j][0];   // broadcast, rows 0..3
                acc[0].x = fmaxf(acc[0].x, v[k].x + q.x);
                acc[0].y = fmaxf(acc[0].y, v[k].y + q.x);
                acc[1].x = fmaxf(acc[1].x, v[k].x + q.y);
                acc[1].y = fmaxf(acc[1].y, v[k].y + q.y);
                acc[2].x = fmaxf(acc[2].x, v[k].x + q.z);
                acc[2].y = fmaxf(acc[2].y, v[k].y + q.z);
                acc[3].x = fmaxf(acc[3].x, v[k].x + q.w);
                acc[3].y = fmaxf(acc[3].y, v[k].y + q.w);
            }
        }
        #pragma unroll
        for (int r = 0; r < 4; r++)
            *(float2*)&sacc[w][r][lane * 2] = acc[r];
        __syncthreads();

        float mv = *sminv;
        for (int e = tid; e < 4 * 128; e += 256) {
            int r = e >> 7, cx = e & 127;
            float m = fmaxf(fmaxf(sacc[0][r][cx], sacc[1][r][cx]),
                            fmaxf(sacc[2][r][cx], sacc[3][r][cx]));
            if (m == -FLT_MAX) m = mv;             // fully-masked row -> global min fill
            out[((size_t)(b * Ll + l0 + r)) * OUTC + hc * 128 + cx] = m;
        }
    } else {
        // ---------------- word embedding gather ----------------
        for (int i = id * 256 + tid; i < Bb * Ll * WD; i += 64 * 256) {
            int bl = i / WD, d = i - bl * WD;
            out[(size_t)bl * OUTC + Hh + d] = word_table[(size_t)word_ids[bl] * WD + d];
        }
    }
}

extern "C" void kernel_launch(void* const* d_in, const int* in_sizes, int n_in,
                              void* d_out, int out_size, void* d_ws, size_t ws_size,
                              hipStream_t stream) {
    const float* bert       = (const float*)d_in[0];
    const int*   p2w        = (const int*)d_in[1];
    const int*   word_ids   = (const int*)d_in[2];
    const int*   char_count = (const int*)d_in[3];
    const int*   char_ids   = (const int*)d_in[4];
    // d_in[5] token_masks_char: consistent with char_count, unused
    const float* word_table = (const float*)d_in[6];
    const float* char_table = (const float*)d_in[7];
    const float* Wih_f = (const float*)d_in[8];
    const float* Whh_f = (const float*)d_in[9];
    const float* bih_f = (const float*)d_in[10];
    const float* bhh_f = (const float*)d_in[11];
    const float* Wih_b = (const float*)d_in[12];
    const float* Whh_b = (const float*)d_in[13];
    const float* bih_b = (const float*)d_in[14];
    const float* bhh_b = (const float*)d_in[15];
    float* out = (float*)d_out;

    float* minp = (float*)d_ws;          // 128 floats
    float* xpt  = minp + 128;            // 2*128*200 floats

    kernel1<<<144, 256, 0, stream>>>(
        bert, char_table, Wih_f, bih_f, bhh_f, Wih_b, bih_b, bhh_b,
        minp, xpt);
    kernel2<<<1856, 256, 0, stream>>>(
        char_ids, char_count, Whh_f, Whh_b, xpt, bert, p2w, minp,
        word_ids, word_table, out);
}